// Round 1
// baseline (206.432 us; speedup 1.0000x reference)
//
#include <hip/hip_runtime.h>
#include <hip/hip_bf16.h>

typedef __attribute__((ext_vector_type(8))) short bf16x8;
typedef __attribute__((ext_vector_type(4))) float f32x4;

#define B_   8
#define C_   64
#define T_   32
#define N_   400
#define H_   2
#define D_   32
#define BT_  256
#define KP_  416      // K (j) padded to multiple of 32 for MFMA
#define MW_  13       // mask words per row (400 bits -> 13 u32)

// workspace layout (bytes)
#define WS_WQEFF 0
#define WS_WKEFF 512
#define WS_MASK  1024
#define WS_PRE   32768   // 102400*64 f32 = 26,214,400 B

// ---------------------------------------------------------------- prep
__global__ __launch_bounds__(256) void gat_prep_kernel(
    const float* __restrict__ Wq, const float* __restrict__ Wk,
    const float* __restrict__ a_src, const float* __restrict__ a_dst,
    const int* __restrict__ gso,
    float* __restrict__ wq_eff, float* __restrict__ wk_eff,
    unsigned int* __restrict__ maskbits)
{
  const int tid = threadIdx.x;
  if (blockIdx.x == 0) {
    // fold attention vectors into the projection: w_eff[h][c] = sum_d W[h*D+d][c]*a[h][d]
    int tsel = (tid < 128) ? tid : tid - 128;
    int h = tsel >> 6, c = tsel & 63;
    const float* W = (tid < 128) ? Wq : Wk;
    const float* a = (tid < 128) ? a_src : a_dst;
    float s = 0.f;
    #pragma unroll
    for (int d = 0; d < D_; ++d) s += W[(h*D_ + d)*C_ + c] * a[h*D_ + d];
    ((tid < 128) ? wq_eff : wk_eff)[h*C_ + c] = s;
  } else {
    int idx = (blockIdx.x - 1) * 256 + tid;
    if (idx < N_ * MW_) {
      int i = idx / MW_, w = idx % MW_;
      unsigned int bits = 0;
      int j0 = w * 32;
      #pragma unroll
      for (int bb = 0; bb < 32; ++bb) {
        int j = j0 + bb;
        if (j < N_ && gso[i*N_ + j] != 0) bits |= (1u << bb);
      }
      maskbits[idx] = bits;
    }
  }
}

// ---------------------------------------------------------------- attention
// one block per (bt, h). LDS map (bytes):
//   [0,26624)        Vt   : bf16 [32][416]  (V^T for this head, j padded w/ 0)
//   [26624,53248)    Pb   : bf16 [32][416]  (P tile, A-fragment friendly)
//       phase-1 alias: xs  f32[64][65] @26624 (16640 B), wvt f32[64][36] @43264 (9216 B)
//   [53248,54848)    ssrc f32[400]
//   [54848,56448)    sdst f32[400]
//   [56448,56704)    wqs  f32[64]
//   [56704,56960)    wks  f32[64]
//   [56960,57088)    linv f32[32]
__global__ __launch_bounds__(256) void gat_attn_kernel(
    const float* __restrict__ x, const float* __restrict__ Wv,
    const float* __restrict__ wq_eff, const float* __restrict__ wk_eff,
    const unsigned int* __restrict__ maskbits,
    float* __restrict__ pre)
{
  __shared__ __align__(16) char smem[57088];
  __hip_bfloat16* Vt = (__hip_bfloat16*)(smem);
  __hip_bfloat16* Pb = (__hip_bfloat16*)(smem + 26624);
  float* xs   = (float*)(smem + 26624);
  float* wvt  = (float*)(smem + 43264);
  float* ssrc = (float*)(smem + 53248);
  float* sdst = (float*)(smem + 54848);
  float* wqs  = (float*)(smem + 56448);
  float* wks  = (float*)(smem + 56704);
  float* linv = (float*)(smem + 56960);

  const int tid = threadIdx.x;
  const int bt  = blockIdx.x >> 1;
  const int h   = blockIdx.x & 1;
  const int b   = bt >> 5;   // T=32
  const int t   = bt & 31;

  // ---- phase 0: stage Wv^T for this head + folded a-vectors; zero Vt j-pad
  #pragma unroll
  for (int it = 0; it < 8; ++it) {
    int idx = it*256 + tid;
    int c = idx & 63, d = idx >> 6;                 // coalesced over c
    wvt[c*36 + d] = Wv[(h*D_ + d)*C_ + c];
  }
  if (tid < 64)       wqs[tid]      = wq_eff[h*C_ + tid];
  else if (tid < 128) wks[tid - 64] = wk_eff[h*C_ + tid - 64];
  for (int k = tid; k < D_*16; k += 256)
    Vt[(k >> 4)*KP_ + 400 + (k & 15)] = __float2bfloat16(0.f);

  // ---- phase 1: V^T (bf16 in LDS) + s_src/s_dst
  const int nl = tid >> 2, dg = tid & 3;           // 64 nodes x 4 d-groups(8)
  for (int n0 = 0; n0 < N_; n0 += 64) {
    __syncthreads();
    #pragma unroll
    for (int it = 0; it < 16; ++it) {
      int idx = it*256 + tid;
      int c = idx >> 6, nn = idx & 63;             // coalesced over n
      int n = n0 + nn;
      xs[c*65 + nn] = (n < N_) ? x[((b*C_ + c)*T_ + t)*N_ + n] : 0.f;
    }
    __syncthreads();
    float a0=0,a1=0,a2=0,a3=0,a4=0,a5=0,a6=0,a7=0;
    float sq = 0.f, sk = 0.f;
    #pragma unroll 8
    for (int c = 0; c < C_; ++c) {
      float xv = xs[c*65 + nl];
      const f32x4* wr = (const f32x4*)(wvt + c*36 + dg*8);
      f32x4 w0 = wr[0], w1 = wr[1];
      a0 += xv * w0.x; a1 += xv * w0.y; a2 += xv * w0.z; a3 += xv * w0.w;
      a4 += xv * w1.x; a5 += xv * w1.y; a6 += xv * w1.z; a7 += xv * w1.w;
      sq += xv * wqs[c];
      sk += xv * wks[c];
    }
    int n = n0 + nl;
    if (n < N_) {
      int db = dg*8;
      Vt[(db+0)*KP_ + n] = __float2bfloat16(a0);
      Vt[(db+1)*KP_ + n] = __float2bfloat16(a1);
      Vt[(db+2)*KP_ + n] = __float2bfloat16(a2);
      Vt[(db+3)*KP_ + n] = __float2bfloat16(a3);
      Vt[(db+4)*KP_ + n] = __float2bfloat16(a4);
      Vt[(db+5)*KP_ + n] = __float2bfloat16(a5);
      Vt[(db+6)*KP_ + n] = __float2bfloat16(a6);
      Vt[(db+7)*KP_ + n] = __float2bfloat16(a7);
      if (dg == 0) ssrc[n] = sq;
      if (dg == 1) sdst[n] = sk;
    }
  }
  __syncthreads();
  // zero P pad columns once (cols 400..415 never touched by score phase)
  for (int k = tid; k < 32*16; k += 256)
    Pb[(k >> 4)*KP_ + 400 + (k & 15)] = __float2bfloat16(0.f);

  // ---- phase 2: per 32-row i-tile: scores -> softmax -> P (bf16) -> MFMA P·V
  const int il = tid >> 3, jc = tid & 7;           // 32 rows x 8 j-chunks(50)
  const int wave = tid >> 6, lane = tid & 63;
  const int rowA = lane & 15, quad = lane >> 4;

  for (int i0 = 0; i0 < N_; i0 += 32) {
    int i = i0 + il;
    float sc[50];
    float m = -3.0e38f;
    if (i < N_) {
      float si = ssrc[i];
      const unsigned int* mrow = maskbits + i*MW_;
      #pragma unroll
      for (int k = 0; k < 50; ++k) {
        int j = jc*50 + k;
        float v = si + sdst[j];
        v = fmaxf(v, 0.2f*v);                      // leaky_relu(0.2)
        unsigned int bit = (mrow[j >> 5] >> (j & 31)) & 1u;
        sc[k] = bit ? v : -1.0e9f;
        m = fmaxf(m, sc[k]);
      }
    }
    m = fmaxf(m, __shfl_xor(m, 1));
    m = fmaxf(m, __shfl_xor(m, 2));
    m = fmaxf(m, __shfl_xor(m, 4));
    float l = 0.f;
    if (i < N_) {
      #pragma unroll
      for (int k = 0; k < 50; ++k) {
        float p = __expf(sc[k] - m);               // masked -> exp(-1e9-m) = 0
        l += p;
        Pb[il*KP_ + jc*50 + k] = __float2bfloat16(p);
      }
    } else {
      #pragma unroll
      for (int k = 0; k < 50; ++k)
        Pb[il*KP_ + jc*50 + k] = __float2bfloat16(0.f);
    }
    l += __shfl_xor(l, 1);
    l += __shfl_xor(l, 2);
    l += __shfl_xor(l, 4);
    if (jc == 0) linv[il] = (i < N_) ? (1.0f / l) : 0.f;
    __syncthreads();

    if (wave < 2) {                                // 2 M-tiles of 16 rows
      f32x4 d0 = {0.f,0.f,0.f,0.f}, d1 = {0.f,0.f,0.f,0.f};
      #pragma unroll
      for (int kt = 0; kt < KP_/32; ++kt) {
        bf16x8 a  = *(const bf16x8*)(Pb + (wave*16 + rowA)*KP_ + kt*32 + quad*8);
        bf16x8 b0 = *(const bf16x8*)(Vt + rowA*KP_        + kt*32 + quad*8);
        bf16x8 b1 = *(const bf16x8*)(Vt + (16 + rowA)*KP_ + kt*32 + quad*8);
        d0 = __builtin_amdgcn_mfma_f32_16x16x32_bf16(a, b0, d0, 0, 0, 0);
        d1 = __builtin_amdgcn_mfma_f32_16x16x32_bf16(a, b1, d1, 0, 0, 0);
      }
      // C/D layout: col = lane&15 (= d), row = quad*4 + reg (= i within tile)
      #pragma unroll
      for (int r = 0; r < 4; ++r) {
        int iL = wave*16 + quad*4 + r;
        int ig = i0 + iL;
        if (ig < N_) {
          float li = linv[iL];
          float* dst = pre + ((size_t)bt*N_ + ig)*C_ + h*D_;
          dst[rowA]      = d0[r] * li;
          dst[16 + rowA] = d1[r] * li;
        }
      }
    }
    __syncthreads();
  }
}

// ---------------------------------------------------------------- layernorm + transpose
__global__ __launch_bounds__(256) void gat_ln_kernel(
    const float* __restrict__ pre, const float* __restrict__ gamma,
    const float* __restrict__ beta, float* __restrict__ out)
{
  __shared__ float tile[C_][65];
  const int tid = threadIdx.x;
  const int bt = blockIdx.x / 7;
  const int nt = blockIdx.x % 7;
  const int b = bt >> 5, t = bt & 31;
  const int n0 = nt * 64;
  const int wave = tid >> 6, lane = tid & 63;
  const float g = gamma[lane], be = beta[lane];
  #pragma unroll
  for (int rr = 0; rr < 16; ++rr) {
    int nl = wave*16 + rr;
    int n = n0 + nl;
    float v = (n < N_) ? pre[((size_t)bt*N_ + n)*C_ + lane] : 0.f;
    float s = v;
    s += __shfl_xor(s, 1);  s += __shfl_xor(s, 2);  s += __shfl_xor(s, 4);
    s += __shfl_xor(s, 8);  s += __shfl_xor(s, 16); s += __shfl_xor(s, 32);
    float mu = s * (1.f/64.f);
    float dv = v - mu;
    float q = dv*dv;
    q += __shfl_xor(q, 1);  q += __shfl_xor(q, 2);  q += __shfl_xor(q, 4);
    q += __shfl_xor(q, 8);  q += __shfl_xor(q, 16); q += __shfl_xor(q, 32);
    float rstd = rsqrtf(q*(1.f/64.f) + 1e-5f);
    tile[lane][nl] = dv * rstd * g + be;
  }
  __syncthreads();
  #pragma unroll
  for (int it = 0; it < 16; ++it) {
    int idx = it*256 + tid;
    int c = idx >> 6, nn = idx & 63;               // n-contiguous per c row
    int n = n0 + nn;
    if (n < N_) out[((b*C_ + c)*T_ + t)*N_ + n] = tile[c][nn];
  }
}

// ---------------------------------------------------------------- launch
extern "C" void kernel_launch(void* const* d_in, const int* in_sizes, int n_in,
                              void* d_out, int out_size, void* d_ws, size_t ws_size,
                              hipStream_t stream) {
  (void)in_sizes; (void)n_in; (void)out_size; (void)ws_size;
  const float* x     = (const float*)d_in[0];
  const float* Wq    = (const float*)d_in[1];
  const float* Wk    = (const float*)d_in[2];
  const float* Wv    = (const float*)d_in[3];
  const float* a_src = (const float*)d_in[4];
  const float* a_dst = (const float*)d_in[5];
  const float* gamma = (const float*)d_in[6];
  const float* beta  = (const float*)d_in[7];
  const int*   gso   = (const int*)d_in[8];
  float* out = (float*)d_out;
  char* ws = (char*)d_ws;

  float* wq_eff = (float*)(ws + WS_WQEFF);
  float* wk_eff = (float*)(ws + WS_WKEFF);
  unsigned int* maskbits = (unsigned int*)(ws + WS_MASK);
  float* pre = (float*)(ws + WS_PRE);

  gat_prep_kernel<<<22, 256, 0, stream>>>(Wq, Wk, a_src, a_dst, gso,
                                          wq_eff, wk_eff, maskbits);
  gat_attn_kernel<<<BT_*H_, 256, 0, stream>>>(x, Wv, wq_eff, wk_eff,
                                              maskbits, pre);
  gat_ln_kernel<<<BT_*7, 256, 0, stream>>>(pre, gamma, beta, out);
}

// Round 2
// 152.520 us; speedup vs baseline: 1.3535x; 1.3535x over previous
//
#include <hip/hip_runtime.h>
#include <hip/hip_bf16.h>

typedef __attribute__((ext_vector_type(8))) short bf16x8;
typedef __attribute__((ext_vector_type(4))) float f32x4;

#define B_   8
#define C_   64
#define T_   32
#define N_   400
#define BT_  256
#define RS_  416          // padded j length (13 * 32)
#define NCH_ 7            // 64-row chunks per bt (7*64 >= 400)

// workspace offsets (bytes)
#define WS_WQ 0                 // 2*64 f32
#define WS_WK 512
#define WS_MB 1024              // 400*16 u32 = 25600
#define WS_SQ 26624             // 256*2*400 f32 = 819200
#define WS_SK 845824            // 819200
#define WS_VG 1665024           // 256*64*416 bf16 = 13631488

// ---------------------------------------------------------------- prep:
// fold a_src/a_dst into Wq/Wk (w_eff[h][c]) + bit-pack gso rows (stride 16 words)
__global__ __launch_bounds__(256) void gat_prep(
    const float* __restrict__ Wq, const float* __restrict__ Wk,
    const float* __restrict__ a_src, const float* __restrict__ a_dst,
    const int* __restrict__ gso,
    float* __restrict__ wq_eff, float* __restrict__ wk_eff,
    unsigned int* __restrict__ mb)
{
  const int tid = threadIdx.x;
  if (blockIdx.x == 0) {
    int tsel = (tid < 128) ? tid : tid - 128;
    int h = tsel >> 6, c = tsel & 63;
    const float* W = (tid < 128) ? Wq : Wk;
    const float* a = (tid < 128) ? a_src : a_dst;
    float s = 0.f;
    #pragma unroll
    for (int d = 0; d < 32; ++d) s += W[(h*32 + d)*C_ + c] * a[h*32 + d];
    ((tid < 128) ? wq_eff : wk_eff)[h*C_ + c] = s;
  } else {
    int idx = (blockIdx.x - 1) * 256 + tid;
    if (idx < N_ * 16) {
      int i = idx >> 4, kw = idx & 15;
      unsigned int bits = 0;
      if (kw < 13) {
        int j0 = kw * 32;
        #pragma unroll
        for (int bb = 0; bb < 32; ++bb) {
          int j = j0 + bb;
          if (j < N_ && gso[i*N_ + j] != 0) bits |= (1u << bb);
        }
      }
      mb[idx] = bits;
    }
  }
}

// ---------------------------------------------------------------- proj:
// V (bf16, [bt*64+o][n] rows padded to 416) + s_src/s_dst (f32) for all nodes
__global__ __launch_bounds__(256, 4) void gat_proj(
    const float* __restrict__ x, const float* __restrict__ Wv,
    const float* __restrict__ wq_eff, const float* __restrict__ wk_eff,
    __hip_bfloat16* __restrict__ Vg, float* __restrict__ sq_g,
    float* __restrict__ sk_g)
{
  __shared__ __align__(16) float xs[64][65];
  __shared__ __align__(16) float wv_s[64][68];
  __shared__ float wqk_s[4][64];
  const int tid = threadIdx.x;
  const int bt = blockIdx.x / NCH_, nc = blockIdx.x % NCH_;
  const int b = bt >> 5, t = bt & 31, n0 = nc * 64;

  #pragma unroll
  for (int it = 0; it < 16; ++it) {
    int idx = it*256 + tid;
    int o = idx >> 6, c = idx & 63;
    wv_s[c][o] = Wv[o*C_ + c];                  // transpose: wv_s[c][o]
  }
  { int typ = tid >> 6, c = tid & 63;
    wqk_s[typ][c] = (typ & 1) ? wk_eff[(typ>>1)*C_ + c]
                              : wq_eff[(typ>>1)*C_ + c]; }
  #pragma unroll
  for (int it = 0; it < 16; ++it) {
    int idx = it*256 + tid;
    int c = idx >> 6, nn = idx & 63;
    int n = n0 + nn;
    xs[c][nn] = (n < N_) ? x[((b*C_ + c)*T_ + t)*N_ + n] : 0.f;
  }
  __syncthreads();

  const int w = tid >> 6, nn = tid & 63;        // wave w: o-group w*16, score type w
  f32x4 a0 = {0,0,0,0}, a1 = {0,0,0,0}, a2 = {0,0,0,0}, a3 = {0,0,0,0};
  float sacc = 0.f;
  #pragma unroll 4
  for (int c = 0; c < 64; ++c) {
    float xv = xs[c][nn];
    const f32x4* wr = (const f32x4*)&wv_s[c][w*16];
    a0 += xv * wr[0];
    a1 += xv * wr[1];
    a2 += xv * wr[2];
    a3 += xv * wr[3];
    sacc = fmaf(xv, wqk_s[w][c], sacc);
  }
  int n = n0 + nn;
  if (n < N_) {
    __hip_bfloat16* vrow = Vg + ((size_t)bt*64 + w*16)*RS_ + n;
    #pragma unroll
    for (int k = 0; k < 4; ++k) vrow[(0*4+k)*RS_] = __float2bfloat16(a0[k]);
    #pragma unroll
    for (int k = 0; k < 4; ++k) vrow[(1*4+k)*RS_] = __float2bfloat16(a1[k]);
    #pragma unroll
    for (int k = 0; k < 4; ++k) vrow[(2*4+k)*RS_] = __float2bfloat16(a2[k]);
    #pragma unroll
    for (int k = 0; k < 4; ++k) vrow[(3*4+k)*RS_] = __float2bfloat16(a3[k]);
    float* sdst = ((w & 1) ? sk_g : sq_g) + ((size_t)bt*2 + (w>>1))*N_ + n;
    *sdst = sacc;
  }
}

// ---------------------------------------------------------------- attn (+LN):
// block = (bt, 64-row i-chunk); 512 threads = 2 heads x 4 itiles of 16 rows.
// Single-pass softmax (fixed shift 12), P built in MFMA A-frag registers.
__global__ __launch_bounds__(512, 4) void gat_attn(
    const __hip_bfloat16* __restrict__ Vg, const float* __restrict__ sq_g,
    const float* __restrict__ sk_g, const unsigned int* __restrict__ mb,
    const float* __restrict__ gamma, const float* __restrict__ beta,
    float* __restrict__ out)
{
  __shared__ __align__(16) __hip_bfloat16 Vt[64 * RS_];   // 53248 B
  __shared__ __align__(16) float sd_s[2 * RS_];           // 3328 B
  __shared__ __align__(16) float ob[64][68];              // 17408 B
  const int tid = threadIdx.x;
  const int bt = blockIdx.x / NCH_, chunk = blockIdx.x % NCH_;
  const int b = bt >> 5, t = bt & 31;
  const int i0 = chunk * 64;

  // stage V (both heads) — flat 16B copy, layout identical to global
  {
    const f32x4* src = (const f32x4*)(Vg + (size_t)bt * 64 * RS_);
    f32x4* dst = (f32x4*)Vt;
    #pragma unroll
    for (int it = 0; it < 7; ++it) {
      int idx = it*512 + tid;
      if (idx < 64 * (RS_/8)) dst[idx] = src[idx];
    }
  }
  #pragma unroll
  for (int h2 = 0; h2 < 2; ++h2)
    if (tid < RS_)
      sd_s[h2*RS_ + tid] = (tid < N_) ? sk_g[((size_t)bt*2 + h2)*N_ + tid] : 0.f;
  __syncthreads();

  const int lane = tid & 63, wave = tid >> 6;
  const int h = wave & 1, itile = wave >> 1;
  const int rowA = lane & 15, quad = lane >> 4;
  const int ibase = i0 + itile*16;

  if (ibase < N_) {
    const int irow = ibase + rowA;
    const float si = sq_g[((size_t)bt*2 + h)*N_ + irow];
    const unsigned int* mrow = mb + irow*16;
    const __hip_bfloat16* vb0 = Vt + (h*32 + rowA)*RS_;
    const __hip_bfloat16* vb1 = vb0 + 16*RS_;
    const float* sdp = sd_s + h*RS_ + quad*8;
    f32x4 d0 = {0,0,0,0}, d1 = {0,0,0,0};
    float lsum = 0.f;
    #pragma unroll
    for (int kt = 0; kt < 13; ++kt) {
      unsigned int mbyte = (mrow[kt] >> (quad*8)) & 0xffu;
      f32x4 s0 = *(const f32x4*)(sdp + kt*32);
      f32x4 s1 = *(const f32x4*)(sdp + kt*32 + 4);
      bf16x8 af;
      #pragma unroll
      for (int jj = 0; jj < 8; ++jj) {
        float sd = (jj < 4) ? s0[jj] : s1[jj - 4];
        float v = si + sd;
        v = fmaxf(v, 0.2f*v);                    // leaky_relu(0.2)
        float e = __expf(v - 12.0f);             // shift-invariant softmax
        float p = ((mbyte >> jj) & 1u) ? e : 0.0f;
        lsum += p;
        union { __hip_bfloat16 hh; short ss; } cv;
        cv.hh = __float2bfloat16(p);
        af[jj] = cv.ss;
      }
      bf16x8 bf0 = *(const bf16x8*)(vb0 + kt*32 + quad*8);
      bf16x8 bf1 = *(const bf16x8*)(vb1 + kt*32 + quad*8);
      d0 = __builtin_amdgcn_mfma_f32_16x16x32_bf16(af, bf0, d0, 0, 0, 0);
      d1 = __builtin_amdgcn_mfma_f32_16x16x32_bf16(af, bf1, d1, 0, 0, 0);
    }
    lsum += __shfl_xor(lsum, 16);
    lsum += __shfl_xor(lsum, 32);
    float lrcp = 1.0f / lsum;
    // C/D layout: col = lane&15 (= d within 16-block), row = quad*4 + reg
    #pragma unroll
    for (int r = 0; r < 4; ++r) {
      float li = __shfl(lrcp, quad*4 + r);
      int rl = itile*16 + quad*4 + r;
      ob[rl][h*32 + rowA]      = d0[r] * li;
      ob[rl][h*32 + 16 + rowA] = d1[r] * li;
    }
  }
  __syncthreads();

  // ---- fused LayerNorm over C=64 (8 lanes per row)
  {
    int rl = tid >> 3;
    int cg = (tid & 7) * 8;
    int n = i0 + rl;
    if (n < N_) {
      f32x4* rp = (f32x4*)&ob[rl][cg];
      f32x4 u0 = rp[0], u1 = rp[1];
      float s = u0.x+u0.y+u0.z+u0.w + u1.x+u1.y+u1.z+u1.w;
      s += __shfl_xor(s, 1); s += __shfl_xor(s, 2); s += __shfl_xor(s, 4);
      float mu = s * (1.f/64.f);
      float q = 0.f;
      #pragma unroll
      for (int k = 0; k < 4; ++k) { float dv = u0[k]-mu; q += dv*dv; }
      #pragma unroll
      for (int k = 0; k < 4; ++k) { float dv = u1[k]-mu; q += dv*dv; }
      q += __shfl_xor(q, 1); q += __shfl_xor(q, 2); q += __shfl_xor(q, 4);
      float rstd = rsqrtf(q*(1.f/64.f) + 1e-5f);
      f32x4 g0 = *(const f32x4*)(gamma + cg), g1 = *(const f32x4*)(gamma + cg + 4);
      f32x4 b0 = *(const f32x4*)(beta + cg),  b1 = *(const f32x4*)(beta + cg + 4);
      rp[0] = (u0 - mu) * rstd * g0 + b0;
      rp[1] = (u1 - mu) * rstd * g1 + b1;
    }
  }
  __syncthreads();

  // ---- transposed store to (B,C,T,N): 64-lane contiguous n runs
  #pragma unroll
  for (int it = 0; it < 8; ++it) {
    int idx = it*512 + tid;
    int c = idx >> 6, nn = idx & 63;
    int n = i0 + nn;
    if (n < N_) out[((b*C_ + c)*T_ + t)*N_ + n] = ob[nn][c];
  }
}

// ---------------------------------------------------------------- launch
extern "C" void kernel_launch(void* const* d_in, const int* in_sizes, int n_in,
                              void* d_out, int out_size, void* d_ws, size_t ws_size,
                              hipStream_t stream) {
  (void)in_sizes; (void)n_in; (void)out_size; (void)ws_size;
  const float* x     = (const float*)d_in[0];
  const float* Wq    = (const float*)d_in[1];
  const float* Wk    = (const float*)d_in[2];
  const float* Wv    = (const float*)d_in[3];
  const float* a_src = (const float*)d_in[4];
  const float* a_dst = (const float*)d_in[5];
  const float* gamma = (const float*)d_in[6];
  const float* beta  = (const float*)d_in[7];
  const int*   gso   = (const int*)d_in[8];
  float* out = (float*)d_out;
  char* ws = (char*)d_ws;

  float* wq_eff = (float*)(ws + WS_WQ);
  float* wk_eff = (float*)(ws + WS_WK);
  unsigned int* mbits = (unsigned int*)(ws + WS_MB);
  float* sq_g = (float*)(ws + WS_SQ);
  float* sk_g = (float*)(ws + WS_SK);
  __hip_bfloat16* Vg = (__hip_bfloat16*)(ws + WS_VG);

  gat_prep<<<26, 256, 0, stream>>>(Wq, Wk, a_src, a_dst, gso,
                                   wq_eff, wk_eff, mbits);
  gat_proj<<<BT_*NCH_, 256, 0, stream>>>(x, Wv, wq_eff, wk_eff,
                                         Vg, sq_g, sk_g);
  gat_attn<<<BT_*NCH_, 512, 0, stream>>>(Vg, sq_g, sk_g, mbits,
                                         gamma, beta, out);
}

// Round 3
// 134.924 us; speedup vs baseline: 1.5300x; 1.1304x over previous
//
#include <hip/hip_runtime.h>
#include <hip/hip_bf16.h>

typedef __attribute__((ext_vector_type(8))) short bf16x8;
typedef __attribute__((ext_vector_type(4))) float f32x4;
typedef __attribute__((ext_vector_type(4))) int i32x4;
typedef __attribute__((ext_vector_type(4))) unsigned int u32x4;

#define B_   8
#define C_   64
#define T_   32
#define N_   400
#define BT_  256
#define NCH_ 7
#define NKT_ 13
#define L2E_ 1.4426950408889634f
#define C2_  (-13.849872392533959f)    /* -9.6 * log2(e) */
#define SH12_ (-17.312340490667560f)   /* -12 * log2(e) */

// workspace offsets (bytes)
#define WS_MB 0           // 400*16 u32 = 25600
#define WS_SQ 25600       // 256*2*400 f32 = 819200
#define WS_SK 844800      // 819200
#define WS_VG 1664000     // 256*13*2*2*512 bf16 = 13631488

#if __has_builtin(__builtin_amdgcn_exp2f)
#define EXP2F(x) __builtin_amdgcn_exp2f(x)
#else
#define EXP2F(x) __expf((x) * 0.6931471805599453f)
#endif

// ---------------------------------------------------------------- proj:
// folds a into Wq/Wk per-wave, projects V into MFMA-B-fragment layout in ws,
// writes log2e-prescaled s_src/s_dst, and (blocks 0..25) bit-packs gso.
__global__ __launch_bounds__(256, 4) void gat_proj(
    const float* __restrict__ x, const float* __restrict__ Wq,
    const float* __restrict__ Wk, const float* __restrict__ Wv,
    const float* __restrict__ a_src, const float* __restrict__ a_dst,
    const int* __restrict__ gso,
    float* __restrict__ sq1, float* __restrict__ sk1,
    __hip_bfloat16* __restrict__ Vg, unsigned int* __restrict__ mb)
{
  __shared__ __align__(16) float xs[64][65];
  __shared__ __align__(16) float wv_s[64][68];
  __shared__ float wqk_s[4][64];
  const int tid = threadIdx.x;
  const int bt = blockIdx.x & 255, nc = blockIdx.x >> 8;  // same bt -> same XCD
  const int b = bt >> 5, t = bt & 31, n0 = nc * 64;
  const int w = tid >> 6, nn = tid & 63;

  { // wave w folds its own score vector: h = w>>1, (w&1)? dst/Wk : src/Wq
    const int h = w >> 1;
    const float* W = (w & 1) ? Wk : Wq;
    const float* a = (w & 1) ? a_dst : a_src;
    float s = 0.f;
    #pragma unroll
    for (int d = 0; d < 32; ++d)
      s += W[(h*32 + d)*C_ + nn] * a[h*32 + d];
    wqk_s[w][nn] = s;
  }
  #pragma unroll
  for (int it = 0; it < 16; ++it) {
    int idx = it*256 + tid;
    int o = idx >> 6, c = idx & 63;
    wv_s[c][o] = Wv[o*C_ + c];
  }
  #pragma unroll
  for (int it = 0; it < 16; ++it) {
    int idx = it*256 + tid;
    int c = idx >> 6, n2 = idx & 63;
    int n = n0 + n2;
    xs[c][n2] = (n < N_) ? x[((b*C_ + c)*T_ + t)*N_ + n] : 0.f;
  }
  __syncthreads();

  f32x4 a0={0,0,0,0}, a1={0,0,0,0}, a2={0,0,0,0}, a3={0,0,0,0};
  float sacc = 0.f;
  #pragma unroll 4
  for (int c = 0; c < 64; ++c) {
    float xv = xs[c][nn];
    const f32x4* wr = (const f32x4*)&wv_s[c][w*16];
    a0 += xv*wr[0]; a1 += xv*wr[1]; a2 += xv*wr[2]; a3 += xv*wr[3];
    sacc = fmaf(xv, wqk_s[w][c], sacc);
  }
  const int n = n0 + nn;
  if (n < N_) {
    int h = w >> 1;
    if (w & 1) sk1[((size_t)bt*2 + h)*N_ + n] = sacc * L2E_;
    else       sq1[((size_t)bt*2 + h)*N_ + n] = fmaf(sacc, L2E_, SH12_);
  }
  if (n < 416) {   // n in [400,416): a's are 0 (xs zero-filled) -> zero pad
    const int kt = n >> 5, q = (n >> 3) & 3, jj = n & 7;
    // wave w -> (h = w>>1, sel = w&1); o = w*16 + r*4 + k, d15 = r*4 + k
    __hip_bfloat16* vp = Vg
        + ((((size_t)bt*NKT_ + kt)*2 + (w>>1))*2 + (w&1))*512
        + q*128 + jj;
    #pragma unroll
    for (int k = 0; k < 4; ++k) vp[(0*4+k)*8] = __float2bfloat16(a0[k]);
    #pragma unroll
    for (int k = 0; k < 4; ++k) vp[(1*4+k)*8] = __float2bfloat16(a1[k]);
    #pragma unroll
    for (int k = 0; k < 4; ++k) vp[(2*4+k)*8] = __float2bfloat16(a2[k]);
    #pragma unroll
    for (int k = 0; k < 4; ++k) vp[(3*4+k)*8] = __float2bfloat16(a3[k]);
  }
  // mask bit-pack (first 26 blocks; independent extra work)
  if (blockIdx.x < 26) {
    int idx = blockIdx.x*256 + tid;
    if (idx < N_*16) {
      int i = idx >> 4, kw = idx & 15;
      unsigned int bits = 0;
      if (kw < 13) {
        int j0 = kw * 32;
        #pragma unroll
        for (int bb = 0; bb < 32; ++bb) {
          int j = j0 + bb;
          if (j < N_ && gso[i*N_ + j] != 0) bits |= (1u << bb);
        }
      }
      mb[idx] = bits;
    }
  }
}

// ---------------------------------------------------------------- attn (+LN):
// block = (bt, 64-row i-chunk); 8 waves = 2 heads x 4 itiles. P built in
// MFMA A-frag registers; row-sum via MFMA against ones; V frags from L2.
__global__ __launch_bounds__(512, 6) void gat_attn(
    const __hip_bfloat16* __restrict__ Vg, const float* __restrict__ sq1,
    const float* __restrict__ sk1, const unsigned int* __restrict__ mb,
    const float* __restrict__ gamma, const float* __restrict__ beta,
    float* __restrict__ out)
{
  __shared__ __align__(16) float sd_s[2][416];
  __shared__ __align__(16) float ob[64][65];
  const int tid = threadIdx.x;
  const int bt = blockIdx.x & 255, chunk = blockIdx.x >> 8;  // bt -> XCD affinity
  const int b = bt >> 5, t = bt & 31;
  const int i0 = chunk * 64;

  if (tid < 416) {
    sd_s[0][tid] = (tid < N_) ? sk1[((size_t)bt*2 + 0)*N_ + tid] : 0.f;
    sd_s[1][tid] = (tid < N_) ? sk1[((size_t)bt*2 + 1)*N_ + tid] : 0.f;
  }
  __syncthreads();

  const int lane = tid & 63, wave = tid >> 6;
  const int h = wave & 1, itile = wave >> 1;
  const int rowA = lane & 15, quad = lane >> 4;
  const int ibase = i0 + itile*16;

  if (ibase < N_) {
    const int irow = ibase + rowA;
    const float si1 = sq1[((size_t)bt*2 + h)*N_ + irow];
    const u32x4* mp = (const u32x4*)(mb + irow*16);
    u32x4 mw0 = mp[0], mw1 = mp[1], mw2 = mp[2];
    unsigned int mw12 = mb[irow*16 + 12];
    const float* sdp = sd_s[h] + quad*8;
    const __hip_bfloat16* vbase = Vg + ((size_t)bt*NKT_*2 + h)*2*512 + lane*8;

    f32x4 d0={0,0,0,0}, d1={0,0,0,0}, d2={0,0,0,0};
    bf16x8 ones;
    #pragma unroll
    for (int k = 0; k < 8; ++k) ones[k] = (short)0x3F80;   // bf16 1.0

    #pragma unroll
    for (int kt = 0; kt < NKT_; ++kt) {
      unsigned int mword = (kt < 4) ? mw0[kt] : (kt < 8) ? mw1[kt-4]
                         : (kt < 12) ? mw2[kt-8] : mw12;
      unsigned int mbyte = (mword >> (quad*8)) & 0xffu;
      f32x4 s0 = *(const f32x4*)(sdp + kt*32);
      f32x4 s1 = *(const f32x4*)(sdp + kt*32 + 4);
      bf16x8 vb0 = *(const bf16x8*)(vbase + kt*2048);
      bf16x8 vb1 = *(const bf16x8*)(vbase + kt*2048 + 512);
      int em[8];
      #pragma unroll
      for (int jj = 0; jj < 8; ++jj) {
        float sd = (jj < 4) ? s0[jj] : s1[jj-4];
        float t1 = si1 + sd;                 // log2e*(raw-12)
        float t2 = fmaf(0.2f, t1, C2_);      // log2e*(0.2*raw-12)
        float v  = fmaxf(t1, t2);            // leaky_relu, log2-domain
        float e  = EXP2F(v);
        int msk = ((int)(mbyte << (31 - jj))) >> 31;   // 0 or ~0
        em[jj] = __float_as_int(e) & msk;              // e or +0.0f
      }
      union { i32x4 i; bf16x8 v; } af;
      af.i.x = (int)__builtin_amdgcn_perm((unsigned)em[1], (unsigned)em[0], 0x07060302u);
      af.i.y = (int)__builtin_amdgcn_perm((unsigned)em[3], (unsigned)em[2], 0x07060302u);
      af.i.z = (int)__builtin_amdgcn_perm((unsigned)em[5], (unsigned)em[4], 0x07060302u);
      af.i.w = (int)__builtin_amdgcn_perm((unsigned)em[7], (unsigned)em[6], 0x07060302u);
      d0 = __builtin_amdgcn_mfma_f32_16x16x32_bf16(af.v, vb0, d0, 0, 0, 0);
      d1 = __builtin_amdgcn_mfma_f32_16x16x32_bf16(af.v, vb1, d1, 0, 0, 0);
      d2 = __builtin_amdgcn_mfma_f32_16x16x32_bf16(af.v, ones, d2, 0, 0, 0);
    }
    // C/D: col = lane&15, row = quad*4 + r ; d2[r] = row-sum (any col)
    #pragma unroll
    for (int r = 0; r < 4; ++r) {
      float li = 1.0f / d2[r];
      int rl = itile*16 + quad*4 + r;
      ob[rl][h*32 + rowA]      = d0[r] * li;
      ob[rl][h*32 + 16 + rowA] = d1[r] * li;
    }
  }
  __syncthreads();

  { // fused LayerNorm over C=64 (8 lanes per row), stride-65 = conflict-free
    int rl = tid >> 3, cgi = tid & 7;
    int n = i0 + rl;
    if (n < N_) {
      float u[8]; float s = 0.f;
      #pragma unroll
      for (int k = 0; k < 8; ++k) { u[k] = ob[rl][cgi*8 + k]; s += u[k]; }
      s += __shfl_xor(s,1); s += __shfl_xor(s,2); s += __shfl_xor(s,4);
      float mu = s * (1.f/64.f);
      float q = 0.f;
      #pragma unroll
      for (int k = 0; k < 8; ++k) { float dv = u[k]-mu; q = fmaf(dv,dv,q); }
      q += __shfl_xor(q,1); q += __shfl_xor(q,2); q += __shfl_xor(q,4);
      float rstd = rsqrtf(q*(1.f/64.f) + 1e-5f);
      #pragma unroll
      for (int k = 0; k < 8; ++k) {
        float g = gamma[cgi*8 + k], be = beta[cgi*8 + k];
        ob[rl][cgi*8 + k] = (u[k]-mu)*rstd*g + be;
      }
    }
  }
  __syncthreads();

  // transposed store to (B,C,T,N): c wave-uniform, n-contiguous lanes
  #pragma unroll
  for (int it = 0; it < 8; ++it) {
    int idx = it*512 + tid;
    int c = idx >> 6, nn2 = idx & 63;
    int n = i0 + nn2;
    if (n < N_) out[((b*C_ + c)*T_ + t)*N_ + n] = ob[nn2][c];
  }
}

// ---------------------------------------------------------------- launch
extern "C" void kernel_launch(void* const* d_in, const int* in_sizes, int n_in,
                              void* d_out, int out_size, void* d_ws, size_t ws_size,
                              hipStream_t stream) {
  (void)in_sizes; (void)n_in; (void)out_size; (void)ws_size;
  const float* x     = (const float*)d_in[0];
  const float* Wq    = (const float*)d_in[1];
  const float* Wk    = (const float*)d_in[2];
  const float* Wv    = (const float*)d_in[3];
  const float* a_src = (const float*)d_in[4];
  const float* a_dst = (const float*)d_in[5];
  const float* gamma = (const float*)d_in[6];
  const float* beta  = (const float*)d_in[7];
  const int*   gso   = (const int*)d_in[8];
  float* out = (float*)d_out;
  char* ws = (char*)d_ws;

  unsigned int* mb = (unsigned int*)(ws + WS_MB);
  float* sq1 = (float*)(ws + WS_SQ);
  float* sk1 = (float*)(ws + WS_SK);
  __hip_bfloat16* Vg = (__hip_bfloat16*)(ws + WS_VG);

  gat_proj<<<BT_*NCH_, 256, 0, stream>>>(x, Wq, Wk, Wv, a_src, a_dst, gso,
                                         sq1, sk1, Vg, mb);
  gat_attn<<<BT_*NCH_, 512, 0, stream>>>(Vg, sq1, sk1, mb,
                                         gamma, beta, out);
}